// Round 1
// baseline (457.331 us; speedup 1.0000x reference)
//
#include <hip/hip_runtime.h>
#include <hip/hip_bf16.h>
#include <math.h>

// Problem constants
#define BB   2
#define NN   2048
#define DIMM 512
#define HH   8
#define DHD  64
#define NC3  1536
#define BN   (BB*NN)     // 4096

// ---------------------------------------------------------------------------
// GEMM: C[M x Nc] = A[M x Kd] * B[Nc x Kd]^T   (both row-major over K)
// 64x64 tile, BK=32, 256 threads, 4x4 micro-tile, k-major LDS (pad 4 floats)
// EPI 0: scatter qkv columns into Q/K/V (b,h,n,d) buffers
// EPI 1: add bias, write to Cout row-major [M x DIMM]
// ---------------------------------------------------------------------------
template<int EPI>
__global__ __launch_bounds__(256) void gemm_abt(
    const float* __restrict__ A, const float* __restrict__ Bw,
    float* __restrict__ Qo, float* __restrict__ Ko, float* __restrict__ Vo,
    const float* __restrict__ bias, float* __restrict__ Cout, int Kd)
{
    __shared__ float As[32][68];
    __shared__ float Bs[32][68];

    const int tid = threadIdx.x;
    const int tx = tid & 15;        // 0..15 -> cols 4*tx..
    const int ty = tid >> 4;        // 0..15 -> rows 4*ty..
    const int row0 = blockIdx.x * 64;
    const int c0   = blockIdx.y * 64;

    const int rA = tid >> 3;          // 0..31
    const int kq = (tid & 7) * 4;     // 0,4,...,28

    float acc[4][4];
#pragma unroll
    for (int i = 0; i < 4; ++i)
#pragma unroll
        for (int j = 0; j < 4; ++j) acc[i][j] = 0.f;

    for (int kt = 0; kt < Kd; kt += 32) {
#pragma unroll
        for (int p = 0; p < 2; ++p) {
            int r = rA + p * 32;
            float4 av = *(const float4*)(A  + (size_t)(row0 + r) * Kd + kt + kq);
            As[kq + 0][r] = av.x; As[kq + 1][r] = av.y;
            As[kq + 2][r] = av.z; As[kq + 3][r] = av.w;
            float4 bv = *(const float4*)(Bw + (size_t)(c0 + r) * Kd + kt + kq);
            Bs[kq + 0][r] = bv.x; Bs[kq + 1][r] = bv.y;
            Bs[kq + 2][r] = bv.z; Bs[kq + 3][r] = bv.w;
        }
        __syncthreads();
#pragma unroll
        for (int kk = 0; kk < 32; ++kk) {
            float4 a = *(const float4*)&As[kk][ty * 4];
            float4 b = *(const float4*)&Bs[kk][tx * 4];
            acc[0][0] += a.x * b.x; acc[0][1] += a.x * b.y;
            acc[0][2] += a.x * b.z; acc[0][3] += a.x * b.w;
            acc[1][0] += a.y * b.x; acc[1][1] += a.y * b.y;
            acc[1][2] += a.y * b.z; acc[1][3] += a.y * b.w;
            acc[2][0] += a.z * b.x; acc[2][1] += a.z * b.y;
            acc[2][2] += a.z * b.z; acc[2][3] += a.z * b.w;
            acc[3][0] += a.w * b.x; acc[3][1] += a.w * b.y;
            acc[3][2] += a.w * b.z; acc[3][3] += a.w * b.w;
        }
        __syncthreads();
    }

    if (EPI == 0) {
        // column tile is fully inside one (part, head): 64 | 512
        int p = c0 >> 9;             // 0=q,1=k,2=v
        int h = (c0 & 511) >> 6;
        float* dst = (p == 0) ? Qo : (p == 1) ? Ko : Vo;
#pragma unroll
        for (int i = 0; i < 4; ++i) {
            int bn = row0 + ty * 4 + i;
            int b = bn >> 11, n = bn & (NN - 1);
            float4 vv = make_float4(acc[i][0], acc[i][1], acc[i][2], acc[i][3]);
            *(float4*)(dst + ((size_t)((b * HH + h) * NN + n)) * DHD + tx * 4) = vv;
        }
    } else {
        float4 bb = *(const float4*)(bias + c0 + tx * 4);
#pragma unroll
        for (int i = 0; i < 4; ++i) {
            int bn = row0 + ty * 4 + i;
            float4 vv = make_float4(acc[i][0] + bb.x, acc[i][1] + bb.y,
                                    acc[i][2] + bb.z, acc[i][3] + bb.w);
            *(float4*)(Cout + (size_t)bn * DIMM + c0 + tx * 4) = vv;
        }
    }
}

// ---------------------------------------------------------------------------
// k softmax stats over seq (axis=-2): per (b,h,d) max and sum(exp(.-max))
// grid = 16 (b*h), block = 256
// ---------------------------------------------------------------------------
__global__ __launch_bounds__(256) void ksoftmax_stats(
    const float* __restrict__ K, float* __restrict__ kmax, float* __restrict__ ksum)
{
    int bh = blockIdx.x;
    const float* Kb = K + (size_t)bh * NN * DHD;
    int d = threadIdx.x & 63;
    int g = threadIdx.x >> 6;   // 0..3

    __shared__ float red[4][64];

    float m = -INFINITY;
    for (int n = g; n < NN; n += 4) m = fmaxf(m, Kb[n * DHD + d]);
    red[g][d] = m;
    __syncthreads();
    if (g == 0) {
        m = fmaxf(fmaxf(red[0][d], red[1][d]), fmaxf(red[2][d], red[3][d]));
        red[0][d] = m;
    }
    __syncthreads();
    m = red[0][d];

    float s = 0.f;
    for (int n = g; n < NN; n += 4) s += __expf(Kb[n * DHD + d] - m);
    __syncthreads();
    red[g][d] = s;
    __syncthreads();
    if (g == 0) {
        s = red[0][d] + red[1][d] + red[2][d] + red[3][d];
        kmax[bh * 64 + d] = m;
        ksum[bh * 64 + d] = s;
    }
}

// ---------------------------------------------------------------------------
// Partial M[d,e] = sum_i ksm[i,d] * qsm[i,e] over a chunk of 128 rows.
// grid = (16 bh, 16 chunks), block = 64 (one wave). q softmax done in-wave.
// ---------------------------------------------------------------------------
__global__ __launch_bounds__(64) void compute_Mpart(
    const float* __restrict__ Q, const float* __restrict__ K,
    const float* __restrict__ kmax, const float* __restrict__ ksum,
    float* __restrict__ Mpart)
{
    int bh = blockIdx.x;
    int chunk = blockIdx.y;
    int lane = threadIdx.x;

    const float* Qb = Q + (size_t)bh * NN * DHD;
    const float* Kb = K + (size_t)bh * NN * DHD;
    float km = kmax[bh * 64 + lane];
    float ks = ksum[bh * 64 + lane];

    float acc[64];
#pragma unroll
    for (int d = 0; d < 64; ++d) acc[d] = 0.f;

    for (int r = 0; r < 128; ++r) {
        int i = chunk * 128 + r;
        float qv = Qb[(size_t)i * DHD + lane];
        // wave-wide softmax over 64 lanes (head dim)
        float mx = qv;
#pragma unroll
        for (int off = 32; off; off >>= 1) mx = fmaxf(mx, __shfl_xor(mx, off, 64));
        float e = __expf(qv - mx);
        float sum = e;
#pragma unroll
        for (int off = 32; off; off >>= 1) sum += __shfl_xor(sum, off, 64);
        float qs = e / sum;

        float kv = Kb[(size_t)i * DHD + lane];
        float ksm = __expf(kv - km) / ks;

#pragma unroll
        for (int d = 0; d < 64; ++d) {
            float kd = __shfl(ksm, d, 64);
            acc[d] += kd * qs;
        }
    }

    float* Mp = Mpart + ((size_t)(bh * 16 + chunk)) * 4096;
#pragma unroll
    for (int d = 0; d < 64; ++d) Mp[d * 64 + lane] = acc[d];
}

// ---------------------------------------------------------------------------
// Reduce partial M over 16 chunks. grid = 16, block = 256.
// ---------------------------------------------------------------------------
__global__ __launch_bounds__(256) void reduce_Mpart(
    const float* __restrict__ Mpart, float* __restrict__ M)
{
    int bh = blockIdx.x;
    for (int idx = threadIdx.x; idx < 4096; idx += 256) {
        float s = 0.f;
        for (int c = 0; c < 16; ++c)
            s += Mpart[((size_t)(bh * 16 + c)) * 4096 + idx];
        M[(size_t)bh * 4096 + idx] = s;
    }
}

// ---------------------------------------------------------------------------
// out1[b,n,h*64+e] = sum_d V[b,h,n,d] * M[b,h,d,e]
// grid = (16 bh, 16 row tiles of 128), block = 256 (4 waves x 32 rows)
// ---------------------------------------------------------------------------
__global__ __launch_bounds__(256) void vm_kernel(
    const float* __restrict__ V, const float* __restrict__ M,
    float* __restrict__ out1)
{
    int bh = blockIdx.x;
    int ntile = blockIdx.y;
    int lane = threadIdx.x & 63;
    int w = threadIdx.x >> 6;
    int b = bh >> 3, h = bh & 7;

    const float* Vb = V + (size_t)bh * NN * DHD;
    const float* Mb = M + (size_t)bh * 4096;

    float Mreg[64];
#pragma unroll
    for (int d = 0; d < 64; ++d) Mreg[d] = Mb[d * 64 + lane];

    for (int r = 0; r < 32; ++r) {
        int n = ntile * 128 + w * 32 + r;
        float vv = Vb[(size_t)n * DHD + lane];
        float o = 0.f;
#pragma unroll
        for (int d = 0; d < 64; ++d) {
            float vd = __shfl(vv, d, 64);
            o += vd * Mreg[d];
        }
        out1[((size_t)(b * NN + n)) * DIMM + h * 64 + lane] = o;
    }
}

// ---------------------------------------------------------------------------
extern "C" void kernel_launch(void* const* d_in, const int* in_sizes, int n_in,
                              void* d_out, int out_size, void* d_ws, size_t ws_size,
                              hipStream_t stream)
{
    const float* x     = (const float*)d_in[0];   // (2,2048,512)
    const float* w_qkv = (const float*)d_in[1];   // (1536,512)
    const float* w_out = (const float*)d_in[2];   // (512,512)
    const float* b_out = (const float*)d_in[3];   // (512,)
    float* out = (float*)d_out;                   // (2,2048,512)

    float* ws = (float*)d_ws;
    float* Q    = ws;                       // 2*8*2048*64 = 2,097,152
    float* K    = Q + 2097152;
    float* V    = K + 2097152;
    float* kmax = V + 2097152;              // 1024
    float* ksum = kmax + 1024;              // 1024
    float* Mp   = ksum + 1024;              // 16*16*4096 = 1,048,576
    float* Mm   = Mp + 1048576;             // 65,536
    float* out1 = Mm + 65536;               // 4096*512 = 2,097,152
    // total ~ 36.3 MB

    // 1) qkv projection, scatter into Q/K/V (b,h,n,d)
    gemm_abt<0><<<dim3(BN / 64, NC3 / 64), 256, 0, stream>>>(
        x, w_qkv, Q, K, V, nullptr, nullptr, DIMM);

    // 2) k softmax stats (over seq)
    ksoftmax_stats<<<dim3(BB * HH), 256, 0, stream>>>(K, kmax, ksum);

    // 3) partial M = K_sm^T * Q_sm
    compute_Mpart<<<dim3(BB * HH, 16), 64, 0, stream>>>(Q, K, kmax, ksum, Mp);

    // 4) reduce partials
    reduce_Mpart<<<dim3(BB * HH), 256, 0, stream>>>(Mp, Mm);

    // 5) out1 = V * M, written in (b, n, h*dh) layout
    vm_kernel<<<dim3(BB * HH, 16), 256, 0, stream>>>(V, Mm, out1);

    // 6) final projection + bias
    gemm_abt<1><<<dim3(BN / 64, DIMM / 64), 256, 0, stream>>>(
        out1, w_out, nullptr, nullptr, nullptr, b_out, out, DIMM);
}

// Round 2
// 90.278 us; speedup vs baseline: 5.0658x; 5.0658x over previous
//
#include <hip/hip_runtime.h>
#include <math.h>

// Problem constants
#define BB   2
#define NN   2048
#define DIMM 512
#define HH   8
#define DHD  64
#define NC3  1536
#define BN   (BB*NN)     // 4096

typedef __attribute__((ext_vector_type(8))) short short8;
typedef __attribute__((ext_vector_type(4))) float f32x4;
typedef unsigned short ushort_t;

__device__ inline unsigned short f2bf(float f) {
    unsigned u = __float_as_uint(f);
    unsigned r = (u + 0x7FFFu + ((u >> 16) & 1u)) >> 16;   // RNE
    return (unsigned short)r;
}

// XOR-swizzle within an 8KB [128 rows x 64B] tile: spread 16B granules so
// ds_read_b128 column reads (16 lanes, 16 consecutive rows) hit 8 banks (2-way = free).
#define SWZ(P) ((P) ^ ((((P) >> 7) & 3) << 4))

// ---------------------------------------------------------------------------
// fp32 -> bf16 convert, 4 elems/thread
// ---------------------------------------------------------------------------
__global__ __launch_bounds__(256) void f2b4(const float* __restrict__ s,
                                            ushort_t* __restrict__ d, int n)
{
    int i = (blockIdx.x * 256 + threadIdx.x) * 4;
    if (i >= n) return;
    float4 v = *(const float4*)(s + i);
    ushort4 u;
    u.x = f2bf(v.x); u.y = f2bf(v.y); u.z = f2bf(v.z); u.w = f2bf(v.w);
    *(ushort4*)(d + i) = u;
}

// ---------------------------------------------------------------------------
// bf16 MFMA GEMM: C[M x Nc] = A[M x Kd] * B[Nc x Kd]^T
// 128x128 tile, BK=32, 256 threads = 4 waves (2x2), 16x16x32 bf16 MFMA.
// EPI 0 (qkv): scatter q,k -> fp32 (b,h,n,d); v -> bf16 (b*n, h*64+d)
// EPI 1 (out): B is per-batch (W2T + b*512*512); add bias; fp32 out.
// ---------------------------------------------------------------------------
template<int EPI>
__global__ __launch_bounds__(256) void mgemm(
    const ushort_t* __restrict__ A, const ushort_t* __restrict__ B, int Kd,
    float* __restrict__ Qf, float* __restrict__ Kf, ushort_t* __restrict__ Vb,
    const float* __restrict__ bias, float* __restrict__ Out)
{
    __shared__ __align__(16) char smem[16384];   // As [0,8K), Bs [8K,16K)

    const int tid  = threadIdx.x;
    const int wave = tid >> 6, lane = tid & 63;
    const int wr = wave >> 1, wc = wave & 1;
    const int row0 = blockIdx.x * 128;
    const int c0   = blockIdx.y * 128;

    const ushort_t* Bp = B;
    if (EPI == 1) Bp = B + (size_t)(row0 >> 11) * (DIMM * DIMM);

    f32x4 acc[4][4];
#pragma unroll
    for (int i = 0; i < 4; ++i)
#pragma unroll
        for (int j = 0; j < 4; ++j) acc[i][j] = (f32x4){0.f, 0.f, 0.f, 0.f};

    for (int kt = 0; kt < Kd; kt += 32) {
        // ---- stage A,B tiles (128x32 bf16 each) with swizzled LDS writes
#pragma unroll
        for (int it = 0; it < 2; ++it) {
            int c = tid + it * 256;          // 16B chunk id, 0..511
            int r = c >> 2, g = c & 3;
            int P = c * 16;
            int dsw = SWZ(P);
            *(short8*)(smem + dsw) =
                *(const short8*)(A + (size_t)(row0 + r) * Kd + kt + g * 8);
            *(short8*)(smem + 8192 + dsw) =
                *(const short8*)(Bp + (size_t)(c0 + r) * Kd + kt + g * 8);
        }
        __syncthreads();

        short8 af[4], bfr[4];
#pragma unroll
        for (int i = 0; i < 4; ++i) {
            int Pa = (wr * 64 + i * 16 + (lane & 15)) * 64 + (lane >> 4) * 16;
            af[i]  = *(const short8*)(smem + SWZ(Pa));
            int Pb = (wc * 64 + i * 16 + (lane & 15)) * 64 + (lane >> 4) * 16;
            bfr[i] = *(const short8*)(smem + 8192 + SWZ(Pb));
        }
#pragma unroll
        for (int i = 0; i < 4; ++i)
#pragma unroll
            for (int j = 0; j < 4; ++j)
                acc[i][j] = __builtin_amdgcn_mfma_f32_16x16x32_bf16(
                    af[i], bfr[j], acc[i][j], 0, 0, 0);
        __syncthreads();
    }

    // ---- epilogue. C/D: col = lane&15, row = (lane>>4)*4 + reg
    if (EPI == 0) {
        int p = c0 >> 9;   // uniform: 0=q,1=k,2=v
#pragma unroll
        for (int j = 0; j < 4; ++j) {
            int cj = c0 + wc * 64 + j * 16 + (lane & 15);
            int pc = cj & 511;
            int h = pc >> 6, dd = pc & 63;
#pragma unroll
            for (int i = 0; i < 4; ++i) {
#pragma unroll
                for (int r = 0; r < 4; ++r) {
                    int row = row0 + wr * 64 + i * 16 + (lane >> 4) * 4 + r;
                    int b = row >> 11, n = row & (NN - 1);
                    float v = acc[i][j][r];
                    if (p == 0)
                        Qf[((size_t)(b * HH + h) * NN + n) * DHD + dd] = v;
                    else if (p == 1)
                        Kf[((size_t)(b * HH + h) * NN + n) * DHD + dd] = v;
                    else
                        Vb[(size_t)row * DIMM + pc] = f2bf(v);
                }
            }
        }
    } else {
#pragma unroll
        for (int j = 0; j < 4; ++j) {
            int col = c0 + wc * 64 + j * 16 + (lane & 15);
            float bb = bias[col];
#pragma unroll
            for (int i = 0; i < 4; ++i) {
#pragma unroll
                for (int r = 0; r < 4; ++r) {
                    int row = row0 + wr * 64 + i * 16 + (lane >> 4) * 4 + r;
                    Out[(size_t)row * DIMM + col] = acc[i][j][r] + bb;
                }
            }
        }
    }
}

// ---------------------------------------------------------------------------
// Mpart: per (bh, chunk of 128 rows):
//   qs[r][e] = softmax_e(Q[i]);  ks[r][d] = exp(K[i][d]) (unnormalized)
//   Mp[d][e] += sum_r ks[r][d]*qs[r][e];  ksump[d] = sum_r ks[r][d]
// 256 threads; softmax wave-parallel; GEMM phase 4x4 micro-tile from LDS.
// ---------------------------------------------------------------------------
__global__ __launch_bounds__(256) void mpart(
    const float* __restrict__ Q, const float* __restrict__ K,
    float* __restrict__ Mp, float* __restrict__ ksump)
{
    __shared__ float qs[128][64];
    __shared__ float ks[128][64];

    int bh = blockIdx.x, ch = blockIdx.y;
    int tid = threadIdx.x, w = tid >> 6, lane = tid & 63;
    const float* Qb = Q + ((size_t)bh * NN + ch * 128) * DHD;
    const float* Kb = K + ((size_t)bh * NN + ch * 128) * DHD;

    for (int rr = 0; rr < 32; ++rr) {
        int r = w * 32 + rr;
        float qv = Qb[(size_t)r * DHD + lane];
        float m = qv;
#pragma unroll
        for (int off = 32; off; off >>= 1) m = fmaxf(m, __shfl_xor(m, off));
        float e = __expf(qv - m);
        float s = e;
#pragma unroll
        for (int off = 32; off; off >>= 1) s += __shfl_xor(s, off);
        qs[r][lane] = e / s;
        ks[r][lane] = __expf(Kb[(size_t)r * DHD + lane]);
    }
    __syncthreads();

    int tx = tid & 15, ty = tid >> 4;
    float acc[4][4];
#pragma unroll
    for (int i = 0; i < 4; ++i)
#pragma unroll
        for (int j = 0; j < 4; ++j) acc[i][j] = 0.f;

#pragma unroll 8
    for (int r = 0; r < 128; ++r) {
        float4 a = *(const float4*)&ks[r][ty * 4];
        float4 b = *(const float4*)&qs[r][tx * 4];
        acc[0][0] += a.x * b.x; acc[0][1] += a.x * b.y;
        acc[0][2] += a.x * b.z; acc[0][3] += a.x * b.w;
        acc[1][0] += a.y * b.x; acc[1][1] += a.y * b.y;
        acc[1][2] += a.y * b.z; acc[1][3] += a.y * b.w;
        acc[2][0] += a.z * b.x; acc[2][1] += a.z * b.y;
        acc[2][2] += a.z * b.z; acc[2][3] += a.z * b.w;
        acc[3][0] += a.w * b.x; acc[3][1] += a.w * b.y;
        acc[3][2] += a.w * b.z; acc[3][3] += a.w * b.w;
    }

    float* mp = Mp + ((size_t)(bh * 16 + ch)) * 4096;
#pragma unroll
    for (int i = 0; i < 4; ++i)
        *(float4*)(mp + (ty * 4 + i) * 64 + tx * 4) =
            make_float4(acc[i][0], acc[i][1], acc[i][2], acc[i][3]);

    if (tid < 64) {
        float s = 0.f;
        for (int r = 0; r < 128; ++r) s += ks[r][tid];
        ksump[(bh * 16 + ch) * 64 + tid] = s;
    }
}

// ---------------------------------------------------------------------------
// Reduce partials: M[d][e] = sum_c Mp / sum_c ksump[d].  grid (16,4) x 256.
// ---------------------------------------------------------------------------
__global__ __launch_bounds__(256) void mreduce(
    const float* __restrict__ Mp, const float* __restrict__ ksump,
    float* __restrict__ Mm)
{
    int bh = blockIdx.x, q = blockIdx.y;
    __shared__ float kst[16];
    int tid = threadIdx.x;
    if (tid < 16) {
        float s = 0.f;
        for (int c = 0; c < 16; ++c) s += ksump[(bh * 16 + c) * 64 + q * 16 + tid];
        kst[tid] = s;
    }
    __syncthreads();
#pragma unroll
    for (int ii = 0; ii < 4; ++ii) {
        int idx = q * 1024 + ii * 256 + tid;
        float s = 0.f;
        for (int c = 0; c < 16; ++c)
            s += Mp[((size_t)(bh * 16 + c)) * 4096 + idx];
        Mm[(size_t)bh * 4096 + idx] = s / kst[(idx >> 6) & 15];
    }
}

// ---------------------------------------------------------------------------
// W2T[b][o][h*64+d] = sum_e M[bh][d][e] * w_out[o][h*64+e]   (bf16 out)
// grid (16 bh, 8 o-tiles of 64) x 256
// ---------------------------------------------------------------------------
__global__ __launch_bounds__(256) void w2t_kernel(
    const float* __restrict__ Mm, const float* __restrict__ w_out,
    ushort_t* __restrict__ W2T)
{
    __shared__ float Ms[64][65];
    __shared__ float Wst[64][68];   // [e][o_local]

    int bh = blockIdx.x, ot = blockIdx.y;
    int b = bh >> 3, h = bh & 7;
    int tid = threadIdx.x;

    for (int idx = tid; idx < 4096; idx += 256) {
        int hi = idx >> 6, lo = idx & 63;
        Ms[hi][lo]  = Mm[(size_t)bh * 4096 + idx];
        Wst[lo][hi] = w_out[(size_t)(ot * 64 + hi) * DIMM + h * 64 + lo];
    }
    __syncthreads();

    int d = tid & 63, og = tid >> 6;   // og = wave id
    float acc[16];
#pragma unroll
    for (int oo = 0; oo < 16; ++oo) acc[oo] = 0.f;

    for (int e = 0; e < 64; ++e) {
        float m = Ms[d][e];
#pragma unroll
        for (int k4 = 0; k4 < 4; ++k4) {
            float4 wv = *(const float4*)&Wst[e][og * 16 + k4 * 4];
            acc[k4 * 4 + 0] += m * wv.x;
            acc[k4 * 4 + 1] += m * wv.y;
            acc[k4 * 4 + 2] += m * wv.z;
            acc[k4 * 4 + 3] += m * wv.w;
        }
    }
#pragma unroll
    for (int oo = 0; oo < 16; ++oo) {
        int o = ot * 64 + og * 16 + oo;
        W2T[((size_t)b * DIMM + o) * DIMM + h * 64 + d] = f2bf(acc[oo]);
    }
}

// ---------------------------------------------------------------------------
extern "C" void kernel_launch(void* const* d_in, const int* in_sizes, int n_in,
                              void* d_out, int out_size, void* d_ws, size_t ws_size,
                              hipStream_t stream)
{
    const float* x     = (const float*)d_in[0];   // (2,2048,512)
    const float* w_qkv = (const float*)d_in[1];   // (1536,512)
    const float* w_out = (const float*)d_in[2];   // (512,512)
    const float* b_out = (const float*)d_in[3];   // (512,)
    float* out = (float*)d_out;                   // (2,2048,512)

    char* w = (char*)d_ws;
    ushort_t* xb   = (ushort_t*)(w);               // 4,194,304 B
    ushort_t* wqb  = (ushort_t*)(w + 4194304);     // 1,572,864 B
    float*    Qf   = (float*)   (w + 5767168);     // 8,388,608 B
    float*    Kf   = (float*)   (w + 14155776);    // 8,388,608 B
    ushort_t* Vb   = (ushort_t*)(w + 22544384);    // 4,194,304 B
    float*    Mp   = (float*)   (w + 26738688);    // 4,194,304 B
    float*    ksum = (float*)   (w + 30932992);    //    65,536 B
    float*    Mm   = (float*)   (w + 30998528);    //   262,144 B
    ushort_t* W2T  = (ushort_t*)(w + 31260672);    // 1,048,576 B  (end ~32.3 MB)

    // 1) convert x, w_qkv to bf16
    f2b4<<<dim3(BN * DIMM / 1024), 256, 0, stream>>>(x, xb, BN * DIMM);
    f2b4<<<dim3(NC3 * DIMM / 1024), 256, 0, stream>>>(w_qkv, wqb, NC3 * DIMM);

    // 2) qkv projection (MFMA), scatter Q/K fp32 (b,h,n,d), V bf16 (bn, hd)
    mgemm<0><<<dim3(BN / 128, NC3 / 128), 256, 0, stream>>>(
        xb, wqb, DIMM, Qf, Kf, Vb, nullptr, nullptr);

    // 3) partial M + partial k-softmax denominator
    mpart<<<dim3(BB * HH, 16), 256, 0, stream>>>(Qf, Kf, Mp, ksum);

    // 4) reduce partials -> M
    mreduce<<<dim3(BB * HH, 4), 256, 0, stream>>>(Mp, ksum, Mm);

    // 5) fold M into w_out: W2T[b][o][hd] (bf16)
    w2t_kernel<<<dim3(BB * HH, 8), 256, 0, stream>>>(Mm, w_out, W2T);

    // 6) out = Vb @ W2T^T + bias (MFMA, per-batch B)
    mgemm<1><<<dim3(BN / 128, DIMM / 128), 256, 0, stream>>>(
        Vb, W2T, DIMM, nullptr, nullptr, nullptr, b_out, out);
}

// Round 3
// 84.824 us; speedup vs baseline: 5.3916x; 1.0643x over previous
//
#include <hip/hip_runtime.h>
#include <hip/hip_bf16.h>
#include <math.h>

// Problem constants
#define BB   2
#define NN   2048
#define DIMM 512
#define HH   8
#define DHD  64
#define NC3  1536
#define BN   (BB*NN)     // 4096

typedef __attribute__((ext_vector_type(8))) short short8;
typedef __attribute__((ext_vector_type(4))) float f32x4;
typedef unsigned short u16t;

__device__ inline short bfc(float f) {
    __hip_bfloat16 h = __float2bfloat16(f);
    return *reinterpret_cast<short*>(&h);
}
__device__ inline float bf2f(u16t u) {
    return __uint_as_float(((unsigned)u) << 16);
}

// XOR-swizzle of 16B granules within a [rows x 64B] LDS tile (read==write mapping)
#define SWZ(P) ((P) ^ ((((P) >> 7) & 3) << 4))

// ---------------------------------------------------------------------------
// qkv GEMM: QKV[4096 x 1536] (bf16) = x[4096 x 512](f32) @ w_qkv[1536 x 512]^T(f32)
// fp32->bf16 conversion fused into staging. 128x128 tile, BK=32, 4 waves 2x2.
// Reg-prefetch of next K-tile; XCD-swizzled block ids.
// ---------------------------------------------------------------------------
__global__ __launch_bounds__(256) void qkvgemm(
    const float* __restrict__ A, const float* __restrict__ Bw,
    u16t* __restrict__ QKV)
{
    __shared__ __align__(16) char smem[16384];   // As [0,8K), Bs [8K,16K)

    const int tid  = threadIdx.x;
    const int wave = tid >> 6, lane = tid & 63;
    const int wr = wave >> 1, wc = wave & 1;

    // XCD-aware bijective swizzle (nwg = 32*12 = 384, % 8 == 0)
    int bid = blockIdx.y * gridDim.x + blockIdx.x;
    int nwg = gridDim.x * gridDim.y;
    int swz = (bid & 7) * (nwg >> 3) + (bid >> 3);
    const int row0 = (swz & 31) * 128;       // gridDim.x == 32
    const int c0   = (swz >> 5) * 128;

    float4 ra[2][2], rb[2][2];

#define QLOAD(KT) {                                                           \
    _Pragma("unroll")                                                         \
    for (int it = 0; it < 2; ++it) {                                          \
        int c = tid + it * 256, r = c >> 2, g = c & 3;                        \
        const float* pa = A + (size_t)(row0 + r) * DIMM + (KT) + g * 8;       \
        ra[it][0] = *(const float4*)pa; ra[it][1] = *(const float4*)(pa + 4); \
        const float* pb = Bw + (size_t)(c0 + r) * DIMM + (KT) + g * 8;        \
        rb[it][0] = *(const float4*)pb; rb[it][1] = *(const float4*)(pb + 4); \
    } }

#define QWRITE() {                                                            \
    _Pragma("unroll")                                                         \
    for (int it = 0; it < 2; ++it) {                                          \
        int P = (tid + it * 256) * 16;                                        \
        short8 av, bv;                                                        \
        av[0]=bfc(ra[it][0].x); av[1]=bfc(ra[it][0].y);                       \
        av[2]=bfc(ra[it][0].z); av[3]=bfc(ra[it][0].w);                       \
        av[4]=bfc(ra[it][1].x); av[5]=bfc(ra[it][1].y);                       \
        av[6]=bfc(ra[it][1].z); av[7]=bfc(ra[it][1].w);                       \
        bv[0]=bfc(rb[it][0].x); bv[1]=bfc(rb[it][0].y);                       \
        bv[2]=bfc(rb[it][0].z); bv[3]=bfc(rb[it][0].w);                       \
        bv[4]=bfc(rb[it][1].x); bv[5]=bfc(rb[it][1].y);                       \
        bv[6]=bfc(rb[it][1].z); bv[7]=bfc(rb[it][1].w);                       \
        *(short8*)(smem + SWZ(P)) = av;                                       \
        *(short8*)(smem + 8192 + SWZ(P)) = bv;                                \
    } }

    f32x4 acc[4][4];
#pragma unroll
    for (int i = 0; i < 4; ++i)
#pragma unroll
        for (int j = 0; j < 4; ++j) acc[i][j] = (f32x4){0.f, 0.f, 0.f, 0.f};

    QLOAD(0);
    for (int kt = 0; kt < DIMM; kt += 32) {
        QWRITE();
        __syncthreads();
        if (kt + 32 < DIMM) QLOAD(kt + 32);

        short8 af[4], bfr[4];
#pragma unroll
        for (int i = 0; i < 4; ++i) {
            int Pa = (wr * 64 + i * 16 + (lane & 15)) * 64 + (lane >> 4) * 16;
            af[i]  = *(const short8*)(smem + SWZ(Pa));
            int Pb = (wc * 64 + i * 16 + (lane & 15)) * 64 + (lane >> 4) * 16;
            bfr[i] = *(const short8*)(smem + 8192 + SWZ(Pb));
        }
#pragma unroll
        for (int i = 0; i < 4; ++i)
#pragma unroll
            for (int j = 0; j < 4; ++j)
                acc[i][j] = __builtin_amdgcn_mfma_f32_16x16x32_bf16(
                    af[i], bfr[j], acc[i][j], 0, 0, 0);
        __syncthreads();
    }
#undef QLOAD
#undef QWRITE

    // epilogue: bf16 row-major store. C/D: col = lane&15, row = (lane>>4)*4+reg
#pragma unroll
    for (int j = 0; j < 4; ++j) {
        int col = c0 + wc * 64 + j * 16 + (lane & 15);
#pragma unroll
        for (int i = 0; i < 4; ++i) {
#pragma unroll
            for (int r = 0; r < 4; ++r) {
                int row = row0 + wr * 64 + i * 16 + (lane >> 4) * 4 + r;
                QKV[(size_t)row * NC3 + col] = (u16t)bfc(acc[i][j][r]);
            }
        }
    }
}

// ---------------------------------------------------------------------------
// Mpart: per (bh, chunk of 128 rows): q row-softmax (wave-parallel),
// ks = exp(k) unnormalized; Mp[d][e] = sum_r ks[r][d]*qs[r][e]; ksump[d].
// Q,K read as bf16 from QKV (stride 1536).
// ---------------------------------------------------------------------------
__global__ __launch_bounds__(256) void mpart(
    const u16t* __restrict__ QKV, float* __restrict__ Mp, float* __restrict__ ksump)
{
    __shared__ float qs[128][64];
    __shared__ float ks[128][64];

    int bh = blockIdx.x, ch = blockIdx.y;
    int b = bh >> 3, h = bh & 7;
    int tid = threadIdx.x, w = tid >> 6, lane = tid & 63;
    const u16t* Qb = QKV + ((size_t)b * NN + ch * 128) * NC3 + h * 64;
    const u16t* Kb = Qb + 512;

    for (int rr = 0; rr < 32; ++rr) {
        int r = w * 32 + rr;
        float qv = bf2f(Qb[(size_t)r * NC3 + lane]);
        float m = qv;
#pragma unroll
        for (int off = 32; off; off >>= 1) m = fmaxf(m, __shfl_xor(m, off));
        float e = __expf(qv - m);
        float s = e;
#pragma unroll
        for (int off = 32; off; off >>= 1) s += __shfl_xor(s, off);
        qs[r][lane] = e / s;
        ks[r][lane] = __expf(bf2f(Kb[(size_t)r * NC3 + lane]));
    }
    __syncthreads();

    int tx = tid & 15, ty = tid >> 4;
    float acc[4][4];
#pragma unroll
    for (int i = 0; i < 4; ++i)
#pragma unroll
        for (int j = 0; j < 4; ++j) acc[i][j] = 0.f;

#pragma unroll 8
    for (int r = 0; r < 128; ++r) {
        float4 a = *(const float4*)&ks[r][ty * 4];
        float4 b2 = *(const float4*)&qs[r][tx * 4];
        acc[0][0] += a.x * b2.x; acc[0][1] += a.x * b2.y;
        acc[0][2] += a.x * b2.z; acc[0][3] += a.x * b2.w;
        acc[1][0] += a.y * b2.x; acc[1][1] += a.y * b2.y;
        acc[1][2] += a.y * b2.z; acc[1][3] += a.y * b2.w;
        acc[2][0] += a.z * b2.x; acc[2][1] += a.z * b2.y;
        acc[2][2] += a.z * b2.z; acc[2][3] += a.z * b2.w;
        acc[3][0] += a.w * b2.x; acc[3][1] += a.w * b2.y;
        acc[3][2] += a.w * b2.z; acc[3][3] += a.w * b2.w;
    }

    float* mp = Mp + ((size_t)(bh * 16 + ch)) * 4096;
#pragma unroll
    for (int i = 0; i < 4; ++i)
        *(float4*)(mp + (ty * 4 + i) * 64 + tx * 4) =
            make_float4(acc[i][0], acc[i][1], acc[i][2], acc[i][3]);

    if (tid < 64) {
        float s = 0.f;
        for (int r = 0; r < 128; ++r) s += ks[r][tid];
        ksump[(bh * 16 + ch) * 64 + tid] = s;
    }
}

// ---------------------------------------------------------------------------
// mfinal: reduce Mp -> M (normalized by k-softmax denom), then fold into w_out:
//   W2T[b][o][h*64+d] = sum_e M[d][e] * w_out[o][h*64+e]  (bf16)
// grid (16 bh, 4 o-tiles of 128), block 256. M row kept per-lane in 64 regs.
// ---------------------------------------------------------------------------
__global__ __launch_bounds__(256) void mfinal(
    const float* __restrict__ Mp, const float* __restrict__ ksump,
    const float* __restrict__ w_out, u16t* __restrict__ W2T)
{
    __shared__ float kst[64];
    __shared__ float Ms[64][68];
    __shared__ float Wt[64][64];

    int bh = blockIdx.x, ot = blockIdx.y;
    int b = bh >> 3, h = bh & 7;
    int tid = threadIdx.x;
    int d = tid & 63, og = tid >> 6;

    if (tid < 64) {
        float s = 0.f;
        for (int c = 0; c < 16; ++c) s += ksump[(bh * 16 + c) * 64 + tid];
        kst[tid] = s;
    }
    __syncthreads();

    for (int idx = tid; idx < 4096; idx += 256) {
        float s = 0.f;
        for (int c = 0; c < 16; ++c)
            s += Mp[((size_t)(bh * 16 + c)) * 4096 + idx];
        Ms[idx >> 6][idx & 63] = s / kst[idx >> 6];
    }
    __syncthreads();

    float Mreg[64];
#pragma unroll
    for (int e4 = 0; e4 < 16; ++e4) {
        float4 v = *(const float4*)&Ms[d][e4 * 4];
        Mreg[e4 * 4 + 0] = v.x; Mreg[e4 * 4 + 1] = v.y;
        Mreg[e4 * 4 + 2] = v.z; Mreg[e4 * 4 + 3] = v.w;
    }

    for (int sub = 0; sub < 2; ++sub) {
        int ob = ot * 128 + sub * 64;
        __syncthreads();
        {
            int o = tid >> 2, e0 = (tid & 3) * 16;
#pragma unroll
            for (int q = 0; q < 4; ++q)
                *(float4*)&Wt[o][e0 + q * 4] =
                    *(const float4*)&w_out[(size_t)(ob + o) * DIMM + h * 64 + e0 + q * 4];
        }
        __syncthreads();
#pragma unroll
        for (int oo = 0; oo < 16; ++oo) {
            int o = og * 16 + oo;
            float a = 0.f;
#pragma unroll
            for (int e4 = 0; e4 < 16; ++e4) {
                float4 wv = *(const float4*)&Wt[o][e4 * 4];
                a += wv.x * Mreg[e4 * 4 + 0] + wv.y * Mreg[e4 * 4 + 1]
                   + wv.z * Mreg[e4 * 4 + 2] + wv.w * Mreg[e4 * 4 + 3];
            }
            W2T[((size_t)b * DIMM + ob + o) * DIMM + h * 64 + d] = (u16t)bfc(a);
        }
    }
}

// ---------------------------------------------------------------------------
// out GEMM: Out[4096 x 512](f32) = V[4096 x 512](bf16, stride 1536)
//                                  @ W2T_b[512 x 512]^T(bf16) + bias
// 128x64 tile, BK=32, 4 waves 2x2 (wave-tile 64x32), grid 32x8 = 256 blocks.
// ---------------------------------------------------------------------------
__global__ __launch_bounds__(256) void outgemm(
    const u16t* __restrict__ Aq, const u16t* __restrict__ W2T,
    const float* __restrict__ bias, float* __restrict__ Out)
{
    __shared__ __align__(16) char smem[12288];   // A 8KB, B 4KB

    const int tid  = threadIdx.x;
    const int wave = tid >> 6, lane = tid & 63;
    const int wr = wave >> 1, wc = wave & 1;

    int bid = blockIdx.y * gridDim.x + blockIdx.x;   // 256 blocks, % 8 == 0
    int swz = (bid & 7) * 32 + (bid >> 3);
    const int row0 = (swz & 31) * 128;
    const int c0   = (swz >> 5) * 64;
    const u16t* Bp = W2T + (size_t)(row0 >> 11) * (DIMM * DIMM);

    short8 pa[2], pb;

#define OLOAD(KT) {                                                            \
    _Pragma("unroll")                                                          \
    for (int it = 0; it < 2; ++it) {                                           \
        int c = tid + it * 256, r = c >> 2, g = c & 3;                         \
        pa[it] = *(const short8*)(Aq + (size_t)(row0 + r) * NC3 + (KT) + g*8); \
    }                                                                          \
    { int r = tid >> 2, g = tid & 3;                                           \
      pb = *(const short8*)(Bp + (size_t)(c0 + r) * DIMM + (KT) + g * 8); } }

#define OWRITE() {                                                             \
    _Pragma("unroll")                                                          \
    for (int it = 0; it < 2; ++it) {                                           \
        int P = (tid + it * 256) * 16;                                         \
        *(short8*)(smem + SWZ(P)) = pa[it];                                    \
    }                                                                          \
    { int P = tid * 16; *(short8*)(smem + 8192 + SWZ(P)) = pb; } }

    f32x4 acc[4][2];
#pragma unroll
    for (int i = 0; i < 4; ++i)
#pragma unroll
        for (int j = 0; j < 2; ++j) acc[i][j] = (f32x4){0.f, 0.f, 0.f, 0.f};

    OLOAD(0);
    for (int kt = 0; kt < DIMM; kt += 32) {
        OWRITE();
        __syncthreads();
        if (kt + 32 < DIMM) OLOAD(kt + 32);

        short8 af[4], bfr[2];
#pragma unroll
        for (int i = 0; i < 4; ++i) {
            int Pa = (wr * 64 + i * 16 + (lane & 15)) * 64 + (lane >> 4) * 16;
            af[i] = *(const short8*)(smem + SWZ(Pa));
        }
#pragma unroll
        for (int j = 0; j < 2; ++j) {
            int Pb = (wc * 32 + j * 16 + (lane & 15)) * 64 + (lane >> 4) * 16;
            bfr[j] = *(const short8*)(smem + 8192 + SWZ(Pb));
        }
#pragma unroll
        for (int i = 0; i < 4; ++i)
#pragma unroll
            for (int j = 0; j < 2; ++j)
                acc[i][j] = __builtin_amdgcn_mfma_f32_16x16x32_bf16(
                    af[i], bfr[j], acc[i][j], 0, 0, 0);
        __syncthreads();
    }
#undef OLOAD
#undef OWRITE

#pragma unroll
    for (int j = 0; j < 2; ++j) {
        int col = c0 + wc * 32 + j * 16 + (lane & 15);
        float bb = bias[col];
#pragma unroll
        for (int i = 0; i < 4; ++i) {
#pragma unroll
            for (int r = 0; r < 4; ++r) {
                int row = row0 + wr * 64 + i * 16 + (lane >> 4) * 4 + r;
                Out[(size_t)row * DIMM + col] = acc[i][j][r] + bb;
            }
        }
    }
}

// ---------------------------------------------------------------------------
extern "C" void kernel_launch(void* const* d_in, const int* in_sizes, int n_in,
                              void* d_out, int out_size, void* d_ws, size_t ws_size,
                              hipStream_t stream)
{
    const float* x     = (const float*)d_in[0];   // (2,2048,512)
    const float* w_qkv = (const float*)d_in[1];   // (1536,512)
    const float* w_out = (const float*)d_in[2];   // (512,512)
    const float* b_out = (const float*)d_in[3];   // (512,)
    float* out = (float*)d_out;                   // (2,2048,512)

    char* w = (char*)d_ws;
    u16t*  QKV  = (u16t*) (w);              // 12,582,912 B
    float* Mp   = (float*)(w + 12582912);   //  4,194,304 B
    float* ksum = (float*)(w + 16777216);   //     65,536 B
    u16t*  W2T  = (u16t*) (w + 16842752);   //  1,048,576 B  (end ~17.9 MB)

    // 1) qkv projection (fused fp32->bf16), unified bf16 QKV [4096][1536]
    qkvgemm<<<dim3(32, 12), 256, 0, stream>>>(x, w_qkv, QKV);

    // 2) partial M + partial k-softmax denominator
    mpart<<<dim3(BB * HH, 16), 256, 0, stream>>>(QKV, Mp, ksum);

    // 3) reduce partials + fold M into w_out -> W2T (bf16)
    mfinal<<<dim3(BB * HH, 4), 256, 0, stream>>>(Mp, ksum, w_out, W2T);

    // 4) out = V @ W2T^T + bias
    outgemm<<<dim3(32, 8), 256, 0, stream>>>(QKV + 1024, W2T, b_out, out);
}